// Round 7
// baseline (2453.194 us; speedup 1.0000x reference)
//
#include <hip/hip_runtime.h>
#include <hip/hip_bf16.h>
#include <hip/hip_fp16.h>
#include <math.h>

// ---------------------------------------------------------------------------
// GATGNN forward. fp32 math; ea / M(tj) streams stored as fp16 (~130 MB ws).
//   h = x@Wn + bn; ea = leaky_relu(eattr@We + be)        [ea in fp16]
//   per layer:
//     P = h@Wtop                          (fp32 register-tiled GEMM)
//     fused: M = ea@Wbot (fp16 LDS tiles, v_dot2_f32_f16 MACs);
//            ti=sp(P[dst]+M), tj=sp(P[src]+M); M<-tj (fp16);
//            a1 = sp(dot(ti,att_i)+dot(tj,att_j)); a1 stats via atomics
//     edgeB: ew = exp(sp(BN(a1))) inline (no max-subtract: alpha in (0,~6]);
//            agg[dst] += tj*ew; nsum[dst] += ew
//     h = sp(BN(agg/nsum))                (conv_bias cancels in BN)
//   comp attention + seg-softmax over sorted batch + pool + fc
// Round-6 post-mortem: __launch_bounds__(256,8) forced VGPR=32 -> scratch
// spill (WRITE_SIZE 1.1GB). Now (256,4); dot2 keeps regs low.
// ---------------------------------------------------------------------------

typedef unsigned short ushortt;
typedef _Float16 half2v __attribute__((ext_vector_type(2)));

__device__ __forceinline__ float sp_f(float x) {
  return x > 20.0f ? x : __logf(1.0f + __expf(x));
}
__device__ __forceinline__ float h2f(ushortt u) {
  union { ushortt u; __half h; } c; c.u = u;
  return __half2float(c.h);
}
__device__ __forceinline__ ushortt f2h(float f) {
  union { __half h; ushortt u; } c; c.h = __float2half(f);
  return c.u;
}
__device__ __forceinline__ unsigned pack2h(float a, float b) {
  union { _Float16 h[2]; unsigned u; } c;
  c.h[0] = (_Float16)a; c.h[1] = (_Float16)b;
  return c.u;
}
__device__ __forceinline__ float fdot2f(unsigned a, unsigned b, float c) {
  return __builtin_amdgcn_fdot2(__builtin_bit_cast(half2v, a),
                                __builtin_bit_cast(half2v, b), c, false);
}

// Register-tiled GEMM: out[R,64] = act(in[R,K] @ W[K,64] (+ b))
// Block: 256 thr, tile 64 rows x 64 cols; thread: 4 rows x 4 cols.
// LH16: in is fp16; A-tile fp16 row-major; W-tile k-pair-packed half2;
//       MACs via v_dot2_f32_f16. (requires K%8==0)
// FUSE_A: epilogue gathers P[dst],P[src], writes tj (fp16) over out,
//         emits a1 and accumulates sum/sumsq of a1 into stats[0..1].
template<int K, int ACT, int BIAS, int FUSE_A, int LH16, typename IT, typename OT>
__global__ __launch_bounds__(256, LH16 ? 4 : 1) void k_gemm_rt(
    const IT* __restrict__ in, const float* __restrict__ W,
    const float* __restrict__ b, OT* __restrict__ out, int R,
    const float* __restrict__ P, const int* __restrict__ eidx,
    const float* __restrict__ catt, float* __restrict__ a1,
    float* __restrict__ stats)
{
  constexpr int KP  = (K + 3) / 4 * 4;       // fp32 path: k padded to x4
  constexpr int LSf = KP + 4;                // fp32 ins stride (floats)
  constexpr int LSb = K + 8;                 // fp16 ins stride (shorts)
  constexpr size_t INS_B = LH16 ? (size_t)64 * LSb * 2 : (size_t)64 * LSf * 4;
  constexpr size_t WS_B  = LH16 ? (size_t)(K / 2) * 64 * 4 : (size_t)KP * 64 * 4;
  __shared__ __align__(16) unsigned char smem[INS_B + WS_B];
  __shared__ float atts[128];
  __shared__ float ssum[4], ssq[4];
  ushortt*  insb = (ushortt*)smem;
  unsigned* Wp   = (unsigned*)(smem + INS_B);   // LH16: [K/2][64] half2-packed
  float*    insf = (float*)smem;
  float*    Wsf  = (float*)(smem + INS_B);

  const int tx = threadIdx.x;
  const int b0 = blockIdx.x * 64;

  if (LH16) {
    static_assert(!LH16 || (K % 8 == 0), "fp16 path needs K%8==0");
    // W packed: Wp[k2*64+c] = half2(W[2k2][c], W[2k2+1][c])
    for (int i = tx; i < (K / 2) * 64; i += 256) {
      const int k2 = i >> 6;
      const int c = i & 63;
      Wp[i] = pack2h(W[(2 * k2) * 64 + c], W[(2 * k2 + 1) * 64 + c]);
    }
    for (int i = tx; i < 64 * (K / 8); i += 256) {
      const int row = i / (K / 8);
      const int k8 = i % (K / 8);
      long r = b0 + row; if (r >= R) r = R - 1;   // clamp: values unused
      *(uint4*)&insb[row * LSb + k8 * 8] =
          *(const uint4*)&((const ushortt*)in)[r * (long)K + k8 * 8];
    }
  } else {
    for (int i = tx; i < KP * 64; i += 256) {
      const int k = i >> 6;
      Wsf[i] = (k < K) ? W[i] : 0.0f;
    }
    for (int i = tx; i < 64 * (KP / 4); i += 256) {
      const int row = i / (KP / 4);
      const int k4 = i % (KP / 4);
      long r = b0 + row; if (r >= R) r = R - 1;
      float4 v;
      if (K % 4 == 0) {
        v = *(const float4*)&((const float*)in)[r * (long)K + k4 * 4];
      } else {
        float t[4];
        #pragma unroll
        for (int j = 0; j < 4; ++j) {
          const int k = k4 * 4 + j;
          t[j] = (k < K) ? ((const float*)in)[r * (long)K + k] : 0.0f;
        }
        v = make_float4(t[0], t[1], t[2], t[3]);
      }
      *(float4*)&insf[row * LSf + k4 * 4] = v;
    }
  }
  if (FUSE_A) { if (tx < 128) atts[tx] = catt[tx]; }
  __syncthreads();

  const int lr0 = ((tx >> 6) << 4) + (((tx >> 4) & 3) << 2);  // local row base
  const int c0 = (tx & 15) << 2;                               // col base
  float acc[4][4];
  #pragma unroll
  for (int i = 0; i < 4; ++i)
    #pragma unroll
    for (int j = 0; j < 4; ++j) acc[i][j] = 0.0f;

  if (LH16) {
    #pragma unroll
    for (int k8 = 0; k8 < K / 8; ++k8) {
      uint4 av[4], wv[4];
      #pragma unroll
      for (int ri = 0; ri < 4; ++ri)
        av[ri] = *(const uint4*)&insb[(lr0 + ri) * LSb + k8 * 8];
      #pragma unroll
      for (int p = 0; p < 4; ++p)
        wv[p] = *(const uint4*)&Wp[(k8 * 4 + p) * 64 + c0];
      #pragma unroll
      for (int ri = 0; ri < 4; ++ri) {
        const unsigned* ap = (const unsigned*)&av[ri];
        #pragma unroll
        for (int p = 0; p < 4; ++p) {
          const unsigned aa = ap[p];
          acc[ri][0] = fdot2f(aa, wv[p].x, acc[ri][0]);
          acc[ri][1] = fdot2f(aa, wv[p].y, acc[ri][1]);
          acc[ri][2] = fdot2f(aa, wv[p].z, acc[ri][2]);
          acc[ri][3] = fdot2f(aa, wv[p].w, acc[ri][3]);
        }
      }
    }
  } else {
    #pragma unroll 4
    for (int k4 = 0; k4 < KP / 4; ++k4) {
      float4 w[4], a[4];
      #pragma unroll
      for (int kk = 0; kk < 4; ++kk)
        w[kk] = *(const float4*)&Wsf[(k4 * 4 + kk) * 64 + c0];
      #pragma unroll
      for (int ri = 0; ri < 4; ++ri)
        a[ri] = *(const float4*)&insf[(lr0 + ri) * LSf + k4 * 4];
      #pragma unroll
      for (int ri = 0; ri < 4; ++ri) {
        const float* av = (const float*)&a[ri];
        #pragma unroll
        for (int kk = 0; kk < 4; ++kk) {
          acc[ri][0] = fmaf(av[kk], w[kk].x, acc[ri][0]);
          acc[ri][1] = fmaf(av[kk], w[kk].y, acc[ri][1]);
          acc[ri][2] = fmaf(av[kk], w[kk].z, acc[ri][2]);
          acc[ri][3] = fmaf(av[kk], w[kk].w, acc[ri][3]);
        }
      }
    }
  }

  if (!FUSE_A) {
    float4 bias = make_float4(0.f, 0.f, 0.f, 0.f);
    if (BIAS) bias = *(const float4*)&b[c0];
    #pragma unroll
    for (int ri = 0; ri < 4; ++ri) {
      const long r = b0 + lr0 + ri;
      if (r >= R) continue;
      float4 v;
      v.x = acc[ri][0] + bias.x; v.y = acc[ri][1] + bias.y;
      v.z = acc[ri][2] + bias.z; v.w = acc[ri][3] + bias.w;
      if (ACT == 1) {
        v.x = v.x >= 0.f ? v.x : 0.2f * v.x;  v.y = v.y >= 0.f ? v.y : 0.2f * v.y;
        v.z = v.z >= 0.f ? v.z : 0.2f * v.z;  v.w = v.w >= 0.f ? v.w : 0.2f * v.w;
      }
      if (sizeof(OT) == 4) {
        *(float4*)&out[r * 64 + c0] = v;
      } else {
        ushort4 u;
        u.x = f2h(v.x); u.y = f2h(v.y); u.z = f2h(v.z); u.w = f2h(v.w);
        *(ushort4*)&out[r * 64 + c0] = u;
      }
    }
  } else {
    // epilogue: ti/tj, write tj (fp16) over out, attention logit a1, a1 stats
    float s1 = 0.f, s2 = 0.f;
    #pragma unroll
    for (int ri = 0; ri < 4; ++ri) {
      const long e = b0 + lr0 + ri;
      float part = 0.0f;
      if (e < R) {
        const int s = eidx[e];
        const int d = eidx[(long)R + e];
        const float4 Pd = *(const float4*)&P[(long)d * 64 + c0];
        const float4 Ps = *(const float4*)&P[(long)s * 64 + c0];
        float tj[4];
        const float ti0 = sp_f(Pd.x + acc[ri][0]);
        const float ti1 = sp_f(Pd.y + acc[ri][1]);
        const float ti2 = sp_f(Pd.z + acc[ri][2]);
        const float ti3 = sp_f(Pd.w + acc[ri][3]);
        tj[0] = sp_f(Ps.x + acc[ri][0]);
        tj[1] = sp_f(Ps.y + acc[ri][1]);
        tj[2] = sp_f(Ps.z + acc[ri][2]);
        tj[3] = sp_f(Ps.w + acc[ri][3]);
        ushort4 u;
        u.x = f2h(tj[0]); u.y = f2h(tj[1]); u.z = f2h(tj[2]); u.w = f2h(tj[3]);
        *(ushort4*)&out[e * 64 + c0] = u;
        part = ti0 * atts[c0] + ti1 * atts[c0 + 1] + ti2 * atts[c0 + 2] + ti3 * atts[c0 + 3]
             + tj[0] * atts[64 + c0] + tj[1] * atts[64 + c0 + 1]
             + tj[2] * atts[64 + c0 + 2] + tj[3] * atts[64 + c0 + 3];
      }
      #pragma unroll
      for (int off = 8; off; off >>= 1) part += __shfl_xor(part, off);
      if ((tx & 15) == 0 && e < R) {
        const float v = sp_f(part);
        a1[e] = v;
        s1 += v; s2 += v * v;
      }
    }
    s1 += __shfl_xor(s1, 16); s2 += __shfl_xor(s2, 16);
    s1 += __shfl_xor(s1, 32); s2 += __shfl_xor(s2, 32);
    if ((tx & 63) == 0) { ssum[tx >> 6] = s1; ssq[tx >> 6] = s2; }
    __syncthreads();
    if (tx == 0) {
      atomicAdd(&stats[0], ssum[0] + ssum[1] + ssum[2] + ssum[3]);
      atomicAdd(&stats[1], ssq[0] + ssq[1] + ssq[2] + ssq[3]);
    }
  }
}

// edgeB (merged): ew = exp(sp(BN(a1[e]))); agg[dst]+=tj*ew; nsum[dst]+=ew
__global__ __launch_bounds__(256) void k_edgeB(
    const ushortt* __restrict__ M, const int* __restrict__ dstp,
    const float* __restrict__ a1, const float* __restrict__ stats, float invE,
    float* __restrict__ nsum, float* __restrict__ agg, int E)
{
  const float mean = stats[0] * invE;
  const float var = stats[1] * invE - mean * mean;
  const float scl = rsqrtf(var + 1e-5f);
  const int t = threadIdx.x & 63;
  const int wid = threadIdx.x >> 6;
  const long step = (long)gridDim.x * 4;
  for (long e = (long)blockIdx.x * 4 + wid; e < E; e += step) {
    const int d = dstp[e];
    const float w = __expf(sp_f((a1[e] - mean) * scl));
    const float tj = h2f(M[e * 64 + t]);
    atomicAdd(&agg[(long)d * 64 + t], tj * w);
    if (t == 0) atomicAdd(&nsum[d], w);
  }
}

// per-column sum & sumsq of agg[N,64]/nsum[n] into cs[0..63],[64..127] (pre-zeroed)
__global__ __launch_bounds__(256) void k_colstats(
    const float* __restrict__ agg, const float* __restrict__ nsum,
    int N, float* __restrict__ cs)
{
  const int c = threadIdx.x & 63;
  const int r = threadIdx.x >> 6;
  float s = 0.f, s2 = 0.f;
  for (long n = (long)blockIdx.x * 4 + r; n < N; n += (long)gridDim.x * 4) {
    const float sn = nsum[n];
    const float scale = sn > 0.f ? 1.0f / sn : 0.0f;   // isolated nodes: agg=0
    const float v = agg[n * 64 + c] * scale;
    s += v; s2 += v * v;
  }
  __shared__ float b1[256], b2[256];
  b1[threadIdx.x] = s; b2[threadIdx.x] = s2;
  __syncthreads();
  if (threadIdx.x < 64) {
    atomicAdd(&cs[c], b1[c] + b1[64 + c] + b1[128 + c] + b1[192 + c]);
    atomicAdd(&cs[64 + c], b2[c] + b2[64 + c] + b2[128 + c] + b2[192 + c]);
  }
}

// h = sp((agg/nsum - mean_c) * rsqrt(var_c + eps))
__global__ __launch_bounds__(256) void k_hnew(
    const float* __restrict__ agg, const float* __restrict__ nsum,
    const float* __restrict__ cs, float invN, float* __restrict__ h, int N)
{
  const int c = threadIdx.x & 63;
  const int r = threadIdx.x >> 6;
  const float mean = cs[c] * invN;
  const float var = cs[64 + c] * invN - mean * mean;
  const float scl = rsqrtf(var + 1e-5f);
  for (long n = (long)blockIdx.x * 4 + r; n < N; n += (long)gridDim.x * 4) {
    const float sn = nsum[n];
    const float scale = sn > 0.f ? 1.0f / sn : 0.0f;
    h[n * 64 + c] = sp_f((agg[n * 64 + c] * scale - mean) * scl);
  }
}

// composition attention score a[n] = sp(concat(h,gf)@Wc + bc) @ attW + attb
__global__ __launch_bounds__(256) void k_comp(
    const float* __restrict__ h, const float* __restrict__ gf,
    const int* __restrict__ batch, const float* __restrict__ Wc,
    const float* __restrict__ bc, const float* __restrict__ aw,
    const float* __restrict__ ab, float* __restrict__ aN, int N)
{
  __shared__ float Wcs[167 * 32];
  __shared__ float aws[32];
  __shared__ float bcs[32];
  for (int i = threadIdx.x; i < 167 * 32; i += 256) Wcs[i] = Wc[i];
  if (threadIdx.x < 32) { aws[threadIdx.x] = aw[threadIdx.x]; bcs[threadIdx.x] = bc[threadIdx.x]; }
  __syncthreads();
  const int t = threadIdx.x & 63;
  const int wid = threadIdx.x >> 6;
  const int col = t & 31;
  const float ab0 = ab[0];
  const int step = gridDim.x * 4;
  for (int n = blockIdx.x * 4 + wid; n < N; n += step) {
    const int g = batch[n];
    const float hq = h[(long)n * 64 + t];
    const float g1 = gf[(long)g * 103 + t];
    const float g2 = (t < 39) ? gf[(long)g * 103 + 64 + t] : 0.f;
    float acc = bcs[col];
    #pragma unroll 8
    for (int k = 0; k < 64; ++k) acc = fmaf(__shfl(hq, k), Wcs[k * 32 + col], acc);
    #pragma unroll 8
    for (int k = 0; k < 64; ++k) acc = fmaf(__shfl(g1, k), Wcs[(64 + k) * 32 + col], acc);
    #pragma unroll
    for (int k = 0; k < 39; ++k) acc = fmaf(__shfl(g2, k), Wcs[(128 + k) * 32 + col], acc);
    float val = sp_f(acc) * aws[col];
    #pragma unroll
    for (int off = 16; off; off >>= 1) val += __shfl_xor(val, off);
    if (t == 0) aN[n] = val + ab0;
  }
}

// one 64-thread block per graph: seg-softmax over sorted batch + pool + fc
__global__ __launch_bounds__(64) void k_pool(
    const float* __restrict__ h, const float* __restrict__ aN,
    const int* __restrict__ batch, const float* __restrict__ fcW,
    const float* __restrict__ fcb, float* __restrict__ out, int N, int G)
{
  const int g = blockIdx.x;
  const int t = threadIdx.x;
  int lo = 0, hi = N;
  while (lo < hi) { int mid = (lo + hi) >> 1; if (batch[mid] < g) lo = mid + 1; else hi = mid; }
  const int s = lo;
  hi = N;
  while (lo < hi) { int mid = (lo + hi) >> 1; if (batch[mid] < g + 1) lo = mid + 1; else hi = mid; }
  const int e2 = lo;
  if (s >= e2) { if (t == 0) out[g] = fcb[0]; return; }
  float mx = -1e30f;
  for (int i = s + t; i < e2; i += 64) mx = fmaxf(mx, aN[i]);
  #pragma unroll
  for (int off = 32; off; off >>= 1) mx = fmaxf(mx, __shfl_xor(mx, off));
  float se = 0.f;
  for (int i = s + t; i < e2; i += 64) se += __expf(aN[i] - mx);
  #pragma unroll
  for (int off = 32; off; off >>= 1) se += __shfl_xor(se, off);
  float acc = 0.f;
  for (int n = s; n < e2; ++n) {
    const float w = __expf(aN[n] - mx);
    acc = fmaf(h[(long)n * 64 + t], w, acc);
  }
  float part = (acc / se) * fcW[t];
  #pragma unroll
  for (int off = 32; off; off >>= 1) part += __shfl_xor(part, off);
  if (t == 0) out[g] = part + fcb[0];
}

extern "C" void kernel_launch(void* const* d_in, const int* in_sizes, int n_in,
                              void* d_out, int out_size, void* d_ws, size_t ws_size,
                              hipStream_t stream)
{
  const float* x     = (const float*)d_in[0];
  const int*   eidx  = (const int*)  d_in[1];
  const float* eattr = (const float*)d_in[2];
  const int*   batch = (const int*)  d_in[3];
  const float* gfeat = (const float*)d_in[4];
  const float* embnW = (const float*)d_in[5];
  const float* embnb = (const float*)d_in[6];
  const float* embeW = (const float*)d_in[7];
  const float* embeb = (const float*)d_in[8];
  const float* convW = (const float*)d_in[9];
  const float* convA = (const float*)d_in[10];
  // d_in[11] = conv_bias: cancels exactly in training-mode BatchNorm
  const float* compW = (const float*)d_in[12];
  const float* compb = (const float*)d_in[13];
  const float* attW  = (const float*)d_in[14];
  const float* attb  = (const float*)d_in[15];
  const float* fcW   = (const float*)d_in[16];
  const float* fcb   = (const float*)d_in[17];
  float* out = (float*)d_out;

  const int N = in_sizes[0] / 92;
  const int E = in_sizes[1] / 2;
  const int G = in_sizes[4] / 103;

  // workspace layout (~130 MB): fp32 node buffers, fp16 edge streams
  char* pw = (char*)d_ws;
  float* h     = (float*)pw;  pw += (size_t)N * 64 * 4;
  float* Pagg  = (float*)pw;  pw += (size_t)N * 64 * 4;   // P, then agg
  float* aE    = (float*)pw;  pw += (size_t)E * 4;        // a1 (kept)
  float* stats = (float*)pw;  pw += 256 * 4;              // [0..1] BN-E, [64..191] cs
  float* nsum  = (float*)pw;  pw += (size_t)N * 4;        // adjacent to stats (one memset)
  float* aN    = (float*)pw;  pw += (size_t)N * 4;
  pw = (char*)(((size_t)pw + 63) & ~(size_t)63);
  ushortt* ea  = (ushortt*)pw; pw += (size_t)E * 64 * 2;  // fp16
  ushortt* M   = (ushortt*)pw;                            // fp16: M, then tj

  const int gE64 = (E + 63) / 64;
  const int gN64 = (N + 63) / 64;

  k_gemm_rt<92, 0, 1, 0, 0, float, float><<<gN64, 256, 0, stream>>>(
      x, embnW, embnb, h, N, nullptr, nullptr, nullptr, nullptr, nullptr);
  k_gemm_rt<41, 1, 1, 0, 0, float, ushortt><<<gE64, 256, 0, stream>>>(
      eattr, embeW, embeb, ea, E, nullptr, nullptr, nullptr, nullptr, nullptr);

  for (int l = 0; l < 3; ++l) {
    const float* Wl = convW + (size_t)l * 128 * 64;
    const float* Al = convA + (size_t)l * 128;
    hipMemsetAsync(stats, 0, (256 + (size_t)N) * sizeof(float), stream);
    k_gemm_rt<64, 0, 0, 0, 0, float, float><<<gN64, 256, 0, stream>>>(
        h, Wl, nullptr, Pagg, N, nullptr, nullptr, nullptr, nullptr, nullptr);
    k_gemm_rt<64, 0, 0, 1, 1, ushortt, ushortt><<<gE64, 256, 0, stream>>>(
        ea, Wl + 64 * 64, nullptr, M, E, Pagg, eidx, Al, aE, stats);
    hipMemsetAsync(Pagg, 0, (size_t)N * 64 * sizeof(float), stream);  // agg
    k_edgeB<<<(E + 3) / 4, 256, 0, stream>>>(M, eidx + E, aE, stats,
                                             1.0f / (float)E, nsum, Pagg, E);
    k_colstats<<<1024, 256, 0, stream>>>(Pagg, nsum, N, stats + 64);
    k_hnew<<<2048, 256, 0, stream>>>(Pagg, nsum, stats + 64, 1.0f / (float)N, h, N);
  }

  k_comp<<<gN64, 256, 0, stream>>>(h, gfeat, batch, compW, compb, attW, attb, aN, N);
  k_pool<<<G, 64, 0, stream>>>(h, aN, batch, fcW, fcb, out, N, G);

  (void)n_in; (void)out_size; (void)ws_size;
}

// Round 8
// 1286.920 us; speedup vs baseline: 1.9063x; 1.9063x over previous
//
#include <hip/hip_runtime.h>
#include <hip/hip_bf16.h>
#include <hip/hip_fp16.h>
#include <math.h>

// ---------------------------------------------------------------------------
// GATGNN forward. fp32 math + fp32 LDS tiles (round-4 proven, zero-spill);
// ea / M(tj) HBM streams stored fp16 (~130 MB ws).
//   h = x@Wn + bn; ea = leaky_relu(eattr@We + be)        [ea fp16 in HBM]
//   per layer:
//     P = h@Wtop                          (fp32 register-tiled GEMM)
//     fused: M = ea@Wbot; ti=sp(P[dst]+M), tj=sp(P[src]+M); M<-tj (fp16);
//            a1 = sp(dot(ti,att_i)+dot(tj,att_j)); a1 stats via atomics
//     edgeB (merged): ew = exp(sp(BN(a1))) inline (alpha in (0,~6], no
//            max-subtract needed); agg[dst] += tj*ew; nsum[dst] += ew
//     h = sp(BN(agg/nsum))                (conv_bias cancels in BN)
//   comp attention + seg-softmax over sorted batch + pool + fc
// Post-mortem r6/r7: any __launch_bounds__ min-waves arg caused scratch spill
// (r7: 2.3 GB/dispatch). Plain __launch_bounds__(256) everywhere.
// ---------------------------------------------------------------------------

typedef unsigned short ushortt;

__device__ __forceinline__ float sp_f(float x) {
  return x > 20.0f ? x : __logf(1.0f + __expf(x));
}
__device__ __forceinline__ float h2f(ushortt u) {
  union { ushortt u; __half h; } c; c.u = u;
  return __half2float(c.h);
}
__device__ __forceinline__ ushortt f2h(float f) {
  union { __half h; ushortt u; } c; c.h = __float2half(f);
  return c.u;
}
__device__ __forceinline__ float4 h4_to_f4(ushort4 u) {
  return make_float4(h2f(u.x), h2f(u.y), h2f(u.z), h2f(u.w));
}

// Register-tiled GEMM: out[R,64] = act(in[R,K] @ W[K,64] (+ b))
// Block: 256 thr, tile 64 rows x 64 cols; thread: 4 rows x 4 cols.
// LDS tiles are ALWAYS fp32 (round-4 core). FP16IN: global `in` is fp16,
// converted to fp32 during LDS staging (transient regs only).
// FUSE_A: epilogue gathers P[dst],P[src], writes tj (fp16) over out,
//         emits a1 and accumulates sum/sumsq of a1 into stats[0..1].
template<int K, int ACT, int BIAS, int FUSE_A, int FP16IN, typename IT, typename OT>
__global__ __launch_bounds__(256) void k_gemm_rt(
    const IT* __restrict__ in, const float* __restrict__ W,
    const float* __restrict__ b, OT* __restrict__ out, int R,
    const float* __restrict__ P, const int* __restrict__ eidx,
    const float* __restrict__ catt, float* __restrict__ a1,
    float* __restrict__ stats)
{
  constexpr int KP = (K + 3) / 4 * 4;   // k padded to x4 (zero-filled)
  constexpr int LS = KP + 4;            // ins row stride (floats, 16B-aligned)
  __shared__ __align__(16) float ins[64 * LS];
  __shared__ __align__(16) float Ws[KP * 64];
  __shared__ float atts[128];
  __shared__ float ssum[4], ssq[4];

  const int tx = threadIdx.x;
  const int b0 = blockIdx.x * 64;

  for (int i = tx; i < KP * 64; i += 256) {
    const int k = i >> 6;
    Ws[i] = (k < K) ? W[i] : 0.0f;      // W row-major [K][64]; pad rows zero
  }
  if (FP16IN) {
    static_assert(!FP16IN || (K % 8 == 0), "fp16 staging needs K%8==0");
    for (int i = tx; i < 64 * (K / 8); i += 256) {
      const int row = i / (K / 8);
      const int k8 = i % (K / 8);
      long r = b0 + row; if (r >= R) r = R - 1;   // clamp: values unused
      const ushortt* sp = &((const ushortt*)in)[r * (long)K + k8 * 8];
      const ushort4 u0 = *(const ushort4*)sp;
      const ushort4 u1 = *(const ushort4*)(sp + 4);
      *(float4*)&ins[row * LS + k8 * 8]     = h4_to_f4(u0);
      *(float4*)&ins[row * LS + k8 * 8 + 4] = h4_to_f4(u1);
    }
  } else {
    for (int i = tx; i < 64 * (KP / 4); i += 256) {
      const int row = i / (KP / 4);
      const int k4 = i % (KP / 4);
      long r = b0 + row; if (r >= R) r = R - 1;   // clamp: values unused
      float4 v;
      if (K % 4 == 0) {
        v = *(const float4*)&((const float*)in)[r * (long)K + k4 * 4];
      } else {
        float t[4];
        #pragma unroll
        for (int j = 0; j < 4; ++j) {
          const int k = k4 * 4 + j;
          t[j] = (k < K) ? ((const float*)in)[r * (long)K + k] : 0.0f;
        }
        v = make_float4(t[0], t[1], t[2], t[3]);
      }
      *(float4*)&ins[row * LS + k4 * 4] = v;
    }
  }
  if (FUSE_A) { if (tx < 128) atts[tx] = catt[tx]; }
  __syncthreads();

  const int lr0 = ((tx >> 6) << 4) + (((tx >> 4) & 3) << 2);  // local row base
  const int c0 = (tx & 15) << 2;                               // col base
  float acc[4][4];
  #pragma unroll
  for (int i = 0; i < 4; ++i)
    #pragma unroll
    for (int j = 0; j < 4; ++j) acc[i][j] = 0.0f;

  #pragma unroll 4
  for (int k4 = 0; k4 < KP / 4; ++k4) {
    float4 w[4], a[4];
    #pragma unroll
    for (int kk = 0; kk < 4; ++kk)
      w[kk] = *(const float4*)&Ws[(k4 * 4 + kk) * 64 + c0];
    #pragma unroll
    for (int ri = 0; ri < 4; ++ri)
      a[ri] = *(const float4*)&ins[(lr0 + ri) * LS + k4 * 4];
    #pragma unroll
    for (int ri = 0; ri < 4; ++ri) {
      const float* av = (const float*)&a[ri];
      #pragma unroll
      for (int kk = 0; kk < 4; ++kk) {
        acc[ri][0] = fmaf(av[kk], w[kk].x, acc[ri][0]);
        acc[ri][1] = fmaf(av[kk], w[kk].y, acc[ri][1]);
        acc[ri][2] = fmaf(av[kk], w[kk].z, acc[ri][2]);
        acc[ri][3] = fmaf(av[kk], w[kk].w, acc[ri][3]);
      }
    }
  }

  if (!FUSE_A) {
    float4 bias = make_float4(0.f, 0.f, 0.f, 0.f);
    if (BIAS) bias = *(const float4*)&b[c0];
    #pragma unroll
    for (int ri = 0; ri < 4; ++ri) {
      const long r = b0 + lr0 + ri;
      if (r >= R) continue;
      float4 v;
      v.x = acc[ri][0] + bias.x; v.y = acc[ri][1] + bias.y;
      v.z = acc[ri][2] + bias.z; v.w = acc[ri][3] + bias.w;
      if (ACT == 1) {
        v.x = v.x >= 0.f ? v.x : 0.2f * v.x;  v.y = v.y >= 0.f ? v.y : 0.2f * v.y;
        v.z = v.z >= 0.f ? v.z : 0.2f * v.z;  v.w = v.w >= 0.f ? v.w : 0.2f * v.w;
      }
      if (sizeof(OT) == 4) {
        *(float4*)&out[r * 64 + c0] = v;
      } else {
        ushort4 u;
        u.x = f2h(v.x); u.y = f2h(v.y); u.z = f2h(v.z); u.w = f2h(v.w);
        *(ushort4*)&out[r * 64 + c0] = u;
      }
    }
  } else {
    // epilogue: ti/tj, write tj (fp16) over out, attention logit a1, a1 stats
    float s1 = 0.f, s2 = 0.f;
    #pragma unroll
    for (int ri = 0; ri < 4; ++ri) {
      const long e = b0 + lr0 + ri;
      float part = 0.0f;
      if (e < R) {
        const int s = eidx[e];
        const int d = eidx[(long)R + e];
        const float4 Pd = *(const float4*)&P[(long)d * 64 + c0];
        const float4 Ps = *(const float4*)&P[(long)s * 64 + c0];
        float tj[4];
        const float ti0 = sp_f(Pd.x + acc[ri][0]);
        const float ti1 = sp_f(Pd.y + acc[ri][1]);
        const float ti2 = sp_f(Pd.z + acc[ri][2]);
        const float ti3 = sp_f(Pd.w + acc[ri][3]);
        tj[0] = sp_f(Ps.x + acc[ri][0]);
        tj[1] = sp_f(Ps.y + acc[ri][1]);
        tj[2] = sp_f(Ps.z + acc[ri][2]);
        tj[3] = sp_f(Ps.w + acc[ri][3]);
        ushort4 u;
        u.x = f2h(tj[0]); u.y = f2h(tj[1]); u.z = f2h(tj[2]); u.w = f2h(tj[3]);
        *(ushort4*)&out[e * 64 + c0] = u;
        part = ti0 * atts[c0] + ti1 * atts[c0 + 1] + ti2 * atts[c0 + 2] + ti3 * atts[c0 + 3]
             + tj[0] * atts[64 + c0] + tj[1] * atts[64 + c0 + 1]
             + tj[2] * atts[64 + c0 + 2] + tj[3] * atts[64 + c0 + 3];
      }
      #pragma unroll
      for (int off = 8; off; off >>= 1) part += __shfl_xor(part, off);
      if ((tx & 15) == 0 && e < R) {
        const float v = sp_f(part);
        a1[e] = v;
        s1 += v; s2 += v * v;
      }
    }
    s1 += __shfl_xor(s1, 16); s2 += __shfl_xor(s2, 16);
    s1 += __shfl_xor(s1, 32); s2 += __shfl_xor(s2, 32);
    if ((tx & 63) == 0) { ssum[tx >> 6] = s1; ssq[tx >> 6] = s2; }
    __syncthreads();
    if (tx == 0) {
      atomicAdd(&stats[0], ssum[0] + ssum[1] + ssum[2] + ssum[3]);
      atomicAdd(&stats[1], ssq[0] + ssq[1] + ssq[2] + ssq[3]);
    }
  }
}

// edgeB (merged): ew = exp(sp(BN(a1[e]))); agg[dst]+=tj*ew; nsum[dst]+=ew
__global__ __launch_bounds__(256) void k_edgeB(
    const ushortt* __restrict__ M, const int* __restrict__ dstp,
    const float* __restrict__ a1, const float* __restrict__ stats, float invE,
    float* __restrict__ nsum, float* __restrict__ agg, int E)
{
  const float mean = stats[0] * invE;
  const float var = stats[1] * invE - mean * mean;
  const float scl = rsqrtf(var + 1e-5f);
  const int t = threadIdx.x & 63;
  const int wid = threadIdx.x >> 6;
  const long step = (long)gridDim.x * 4;
  for (long e = (long)blockIdx.x * 4 + wid; e < E; e += step) {
    const int d = dstp[e];
    const float w = __expf(sp_f((a1[e] - mean) * scl));
    const float tj = h2f(M[e * 64 + t]);
    atomicAdd(&agg[(long)d * 64 + t], tj * w);
    if (t == 0) atomicAdd(&nsum[d], w);
  }
}

// per-column sum & sumsq of agg[N,64]/nsum[n] into cs[0..63],[64..127] (pre-zeroed)
__global__ __launch_bounds__(256) void k_colstats(
    const float* __restrict__ agg, const float* __restrict__ nsum,
    int N, float* __restrict__ cs)
{
  const int c = threadIdx.x & 63;
  const int r = threadIdx.x >> 6;
  float s = 0.f, s2 = 0.f;
  for (long n = (long)blockIdx.x * 4 + r; n < N; n += (long)gridDim.x * 4) {
    const float sn = nsum[n];
    const float scale = sn > 0.f ? 1.0f / sn : 0.0f;   // isolated nodes: agg=0
    const float v = agg[n * 64 + c] * scale;
    s += v; s2 += v * v;
  }
  __shared__ float b1[256], b2[256];
  b1[threadIdx.x] = s; b2[threadIdx.x] = s2;
  __syncthreads();
  if (threadIdx.x < 64) {
    atomicAdd(&cs[c], b1[c] + b1[64 + c] + b1[128 + c] + b1[192 + c]);
    atomicAdd(&cs[64 + c], b2[c] + b2[64 + c] + b2[128 + c] + b2[192 + c]);
  }
}

// h = sp((agg/nsum - mean_c) * rsqrt(var_c + eps))
__global__ __launch_bounds__(256) void k_hnew(
    const float* __restrict__ agg, const float* __restrict__ nsum,
    const float* __restrict__ cs, float invN, float* __restrict__ h, int N)
{
  const int c = threadIdx.x & 63;
  const int r = threadIdx.x >> 6;
  const float mean = cs[c] * invN;
  const float var = cs[64 + c] * invN - mean * mean;
  const float scl = rsqrtf(var + 1e-5f);
  for (long n = (long)blockIdx.x * 4 + r; n < N; n += (long)gridDim.x * 4) {
    const float sn = nsum[n];
    const float scale = sn > 0.f ? 1.0f / sn : 0.0f;
    h[n * 64 + c] = sp_f((agg[n * 64 + c] * scale - mean) * scl);
  }
}

// composition attention score a[n] = sp(concat(h,gf)@Wc + bc) @ attW + attb
__global__ __launch_bounds__(256) void k_comp(
    const float* __restrict__ h, const float* __restrict__ gf,
    const int* __restrict__ batch, const float* __restrict__ Wc,
    const float* __restrict__ bc, const float* __restrict__ aw,
    const float* __restrict__ ab, float* __restrict__ aN, int N)
{
  __shared__ float Wcs[167 * 32];
  __shared__ float aws[32];
  __shared__ float bcs[32];
  for (int i = threadIdx.x; i < 167 * 32; i += 256) Wcs[i] = Wc[i];
  if (threadIdx.x < 32) { aws[threadIdx.x] = aw[threadIdx.x]; bcs[threadIdx.x] = bc[threadIdx.x]; }
  __syncthreads();
  const int t = threadIdx.x & 63;
  const int wid = threadIdx.x >> 6;
  const int col = t & 31;
  const float ab0 = ab[0];
  const int step = gridDim.x * 4;
  for (int n = blockIdx.x * 4 + wid; n < N; n += step) {
    const int g = batch[n];
    const float hq = h[(long)n * 64 + t];
    const float g1 = gf[(long)g * 103 + t];
    const float g2 = (t < 39) ? gf[(long)g * 103 + 64 + t] : 0.f;
    float acc = bcs[col];
    #pragma unroll 8
    for (int k = 0; k < 64; ++k) acc = fmaf(__shfl(hq, k), Wcs[k * 32 + col], acc);
    #pragma unroll 8
    for (int k = 0; k < 64; ++k) acc = fmaf(__shfl(g1, k), Wcs[(64 + k) * 32 + col], acc);
    #pragma unroll
    for (int k = 0; k < 39; ++k) acc = fmaf(__shfl(g2, k), Wcs[(128 + k) * 32 + col], acc);
    float val = sp_f(acc) * aws[col];
    #pragma unroll
    for (int off = 16; off; off >>= 1) val += __shfl_xor(val, off);
    if (t == 0) aN[n] = val + ab0;
  }
}

// one 64-thread block per graph: seg-softmax over sorted batch + pool + fc
__global__ __launch_bounds__(64) void k_pool(
    const float* __restrict__ h, const float* __restrict__ aN,
    const int* __restrict__ batch, const float* __restrict__ fcW,
    const float* __restrict__ fcb, float* __restrict__ out, int N, int G)
{
  const int g = blockIdx.x;
  const int t = threadIdx.x;
  int lo = 0, hi = N;
  while (lo < hi) { int mid = (lo + hi) >> 1; if (batch[mid] < g) lo = mid + 1; else hi = mid; }
  const int s = lo;
  hi = N;
  while (lo < hi) { int mid = (lo + hi) >> 1; if (batch[mid] < g + 1) lo = mid + 1; else hi = mid; }
  const int e2 = lo;
  if (s >= e2) { if (t == 0) out[g] = fcb[0]; return; }
  float mx = -1e30f;
  for (int i = s + t; i < e2; i += 64) mx = fmaxf(mx, aN[i]);
  #pragma unroll
  for (int off = 32; off; off >>= 1) mx = fmaxf(mx, __shfl_xor(mx, off));
  float se = 0.f;
  for (int i = s + t; i < e2; i += 64) se += __expf(aN[i] - mx);
  #pragma unroll
  for (int off = 32; off; off >>= 1) se += __shfl_xor(se, off);
  float acc = 0.f;
  for (int n = s; n < e2; ++n) {
    const float w = __expf(aN[n] - mx);
    acc = fmaf(h[(long)n * 64 + t], w, acc);
  }
  float part = (acc / se) * fcW[t];
  #pragma unroll
  for (int off = 32; off; off >>= 1) part += __shfl_xor(part, off);
  if (t == 0) out[g] = part + fcb[0];
}

extern "C" void kernel_launch(void* const* d_in, const int* in_sizes, int n_in,
                              void* d_out, int out_size, void* d_ws, size_t ws_size,
                              hipStream_t stream)
{
  const float* x     = (const float*)d_in[0];
  const int*   eidx  = (const int*)  d_in[1];
  const float* eattr = (const float*)d_in[2];
  const int*   batch = (const int*)  d_in[3];
  const float* gfeat = (const float*)d_in[4];
  const float* embnW = (const float*)d_in[5];
  const float* embnb = (const float*)d_in[6];
  const float* embeW = (const float*)d_in[7];
  const float* embeb = (const float*)d_in[8];
  const float* convW = (const float*)d_in[9];
  const float* convA = (const float*)d_in[10];
  // d_in[11] = conv_bias: cancels exactly in training-mode BatchNorm
  const float* compW = (const float*)d_in[12];
  const float* compb = (const float*)d_in[13];
  const float* attW  = (const float*)d_in[14];
  const float* attb  = (const float*)d_in[15];
  const float* fcW   = (const float*)d_in[16];
  const float* fcb   = (const float*)d_in[17];
  float* out = (float*)d_out;

  const int N = in_sizes[0] / 92;
  const int E = in_sizes[1] / 2;
  const int G = in_sizes[4] / 103;

  // workspace layout (~130 MB): fp32 node buffers, fp16 edge streams
  char* pw = (char*)d_ws;
  float* h     = (float*)pw;  pw += (size_t)N * 64 * 4;
  float* Pagg  = (float*)pw;  pw += (size_t)N * 64 * 4;   // P, then agg
  float* aE    = (float*)pw;  pw += (size_t)E * 4;        // a1 (kept)
  float* stats = (float*)pw;  pw += 256 * 4;              // [0..1] BN-E, [64..191] cs
  float* nsum  = (float*)pw;  pw += (size_t)N * 4;        // adjacent to stats (one memset)
  float* aN    = (float*)pw;  pw += (size_t)N * 4;
  pw = (char*)(((size_t)pw + 63) & ~(size_t)63);
  ushortt* ea  = (ushortt*)pw; pw += (size_t)E * 64 * 2;  // fp16
  ushortt* M   = (ushortt*)pw;                            // fp16: M, then tj

  const int gE64 = (E + 63) / 64;
  const int gN64 = (N + 63) / 64;

  k_gemm_rt<92, 0, 1, 0, 0, float, float><<<gN64, 256, 0, stream>>>(
      x, embnW, embnb, h, N, nullptr, nullptr, nullptr, nullptr, nullptr);
  k_gemm_rt<41, 1, 1, 0, 0, float, ushortt><<<gE64, 256, 0, stream>>>(
      eattr, embeW, embeb, ea, E, nullptr, nullptr, nullptr, nullptr, nullptr);

  for (int l = 0; l < 3; ++l) {
    const float* Wl = convW + (size_t)l * 128 * 64;
    const float* Al = convA + (size_t)l * 128;
    hipMemsetAsync(stats, 0, (256 + (size_t)N) * sizeof(float), stream);
    k_gemm_rt<64, 0, 0, 0, 0, float, float><<<gN64, 256, 0, stream>>>(
        h, Wl, nullptr, Pagg, N, nullptr, nullptr, nullptr, nullptr, nullptr);
    k_gemm_rt<64, 0, 0, 1, 1, ushortt, ushortt><<<gE64, 256, 0, stream>>>(
        ea, Wl + 64 * 64, nullptr, M, E, Pagg, eidx, Al, aE, stats);
    hipMemsetAsync(Pagg, 0, (size_t)N * 64 * sizeof(float), stream);  // agg
    k_edgeB<<<(E + 3) / 4, 256, 0, stream>>>(M, eidx + E, aE, stats,
                                             1.0f / (float)E, nsum, Pagg, E);
    k_colstats<<<1024, 256, 0, stream>>>(Pagg, nsum, N, stats + 64);
    k_hnew<<<2048, 256, 0, stream>>>(Pagg, nsum, stats + 64, 1.0f / (float)N, h, N);
  }

  k_comp<<<gN64, 256, 0, stream>>>(h, gfeat, batch, compW, compb, attW, attb, aN, N);
  k_pool<<<G, 64, 0, stream>>>(h, aN, batch, fcW, fcb, out, N, G);

  (void)n_in; (void)out_size; (void)ws_size;
}